// Round 4
// baseline (936.120 us; speedup 1.0000x reference)
//
#include <hip/hip_runtime.h>
#include <hip/hip_bf16.h>
#include <cstdint>
#include <cstddef>

// Shapes: B=4, C=512, H=W=64, N=4096, td=512.
//   x (4,512,64,64) | w_qkv (1536,512) | w_dw (1536,25) | w_pw (1536,8) |
//   w_proj (512,1024) | out (4,512,64,64)
//
// Input dtype is detected at runtime (fp32 vs bf16) by scanning x: fp32 data
// reinterpreted as bf16 words yields ~10% values with exponent >= 0xE6
// (|v|>1e31/inf/nan); genuine bf16 N(0,1) yields none. Output dtype is tied
// to the input dtype.
//
// ws layout (bytes, all 256-aligned; total ~98.7 MiB):
//   [0]        flag (int, 1 = fp32 IO)
//   [256]      w_qkv_bf  (1536*512  bf16)
//   [+...]     w_dw_bf   (1536*25), w_pw_bf (1536*8), w_proj_bf (512*1024)
//   [...]      vk        (512*72 fp32)
//   [...]      qkv       (4,1536,4096) bf16  = 48 MiB
//   [...]      agg       (4,1536,4096) bf16  = 48 MiB
// attn is written IN-PLACE over the dead v-rows (16..23) of each 24-row head
// in qkv/agg; proj GEMM's B-loader maps attn row k -> that physical row.

typedef __hip_bfloat16 bf16;

__device__ __forceinline__ float b2f(bf16 v) { return __bfloat162float(v); }
__device__ __forceinline__ bf16 f2b(float v) { return __float2bfloat16(v); }

// ---- dtype detector: 1 block, writes flag (1 = fp32 inputs) ----
__global__ __launch_bounds__(256) void detect_kernel(
    const unsigned short* __restrict__ xraw, int* __restrict__ flag)
{
    __shared__ int s_bad;
    if (threadIdx.x == 0) s_bad = 0;
    __syncthreads();
    int bad = 0;
    for (int i = threadIdx.x; i < 4096; i += 256) {
        int e = (xraw[i] >> 7) & 0xFF;   // bf16 exponent field
        if (e >= 0xE6) bad++;            // |v| >= ~1e31, inf, or nan
    }
    atomicAdd(&s_bad, bad);
    __syncthreads();
    if (threadIdx.x == 0) *flag = (s_bad >= 8) ? 1 : 0;
}

// ---- weight conversion to canonical bf16 ----
__global__ __launch_bounds__(256) void convert_kernel(
    const void* __restrict__ src, bf16* __restrict__ dst, int n,
    const int* __restrict__ flag)
{
    const int f32 = *flag;
    int i = blockIdx.x * 256 + threadIdx.x;
    if (i >= n) return;
    if (f32) dst[i] = f2b(((const float*)src)[i]);
    else     dst[i] = ((const bf16*)src)[i];
}

#define GEMM_BM 64
#define GEMM_BN 64
#define GEMM_BK 16
#define GEMM_TM 4
#define GEMM_TN 4

// qkv GEMM: C[b] (1536x4096) = A (1536x512) * x[b] (512x4096)
__global__ __launch_bounds__(256) void qkv_gemm_kernel(
    const bf16* __restrict__ A, const void* __restrict__ X,
    bf16* __restrict__ Cm, const int* __restrict__ flag)
{
    const int M = 1536, K = 512, N = 4096;
    const int f32in = *flag;
    const int b = blockIdx.z;
    bf16* Cb = Cm + (size_t)b * M * N;
    const float* Xf = (const float*)X + (size_t)b * K * N;
    const bf16*  Xb = (const bf16*)X + (size_t)b * K * N;

    __shared__ float As[GEMM_BK][GEMM_BM];
    __shared__ float Bs[GEMM_BK][GEMM_BN];

    const int tid = threadIdx.x;
    const int tm = (tid >> 4) * GEMM_TM;
    const int tn = (tid & 15) * GEMM_TN;
    const int m0 = blockIdx.y * GEMM_BM;
    const int n0 = blockIdx.x * GEMM_BN;

    float acc[GEMM_TM][GEMM_TN] = {};

    for (int k0 = 0; k0 < K; k0 += GEMM_BK) {
        #pragma unroll
        for (int i = 0; i < 4; ++i) {
            int idx = tid + i * 256;
            int m = idx >> 4, kk = idx & 15;
            As[kk][m] = b2f(A[(size_t)(m0 + m) * K + (k0 + kk)]);
        }
        #pragma unroll
        for (int i = 0; i < 4; ++i) {
            int idx = tid + i * 256;
            int kk = idx >> 6, n = idx & 63;
            size_t off = (size_t)(k0 + kk) * N + (n0 + n);
            Bs[kk][n] = f32in ? Xf[off] : b2f(Xb[off]);
        }
        __syncthreads();
        #pragma unroll
        for (int kk = 0; kk < GEMM_BK; ++kk) {
            float a[GEMM_TM], bb[GEMM_TN];
            #pragma unroll
            for (int i = 0; i < GEMM_TM; ++i) a[i] = As[kk][tm + i];
            #pragma unroll
            for (int j = 0; j < GEMM_TN; ++j) bb[j] = Bs[kk][tn + j];
            #pragma unroll
            for (int i = 0; i < GEMM_TM; ++i)
                #pragma unroll
                for (int j = 0; j < GEMM_TN; ++j)
                    acc[i][j] += a[i] * bb[j];
        }
        __syncthreads();
    }

    #pragma unroll
    for (int i = 0; i < GEMM_TM; ++i) {
        int m = m0 + tm + i;
        #pragma unroll
        for (int j = 0; j < GEMM_TN; ++j) {
            int n = n0 + tn + j;
            Cb[(size_t)m * N + n] = f2b(acc[i][j]);
        }
    }
}

// proj GEMM: out[b] (512x4096) = w_proj (512x1024) @ attn[b] + x[b]
__global__ __launch_bounds__(256) void proj_gemm_kernel(
    const bf16* __restrict__ A, const bf16* __restrict__ qkv,
    const bf16* __restrict__ agg, const void* __restrict__ X,
    void* __restrict__ Out, const int* __restrict__ flag)
{
    const int M = 512, K = 1024, N = 4096;
    const int f32io = *flag;
    const int b = blockIdx.z;
    const float* Xf = (const float*)X + (size_t)b * M * N;
    const bf16*  Xb = (const bf16*)X + (size_t)b * M * N;
    float* Of = (float*)Out + (size_t)b * M * N;
    bf16*  Ob = (bf16*)Out + (size_t)b * M * N;

    __shared__ float As[GEMM_BK][GEMM_BM];
    __shared__ float Bs[GEMM_BK][GEMM_BN];

    const int tid = threadIdx.x;
    const int tm = (tid >> 4) * GEMM_TM;
    const int tn = (tid & 15) * GEMM_TN;
    const int m0 = blockIdx.y * GEMM_BM;
    const int n0 = blockIdx.x * GEMM_BN;

    float acc[GEMM_TM][GEMM_TN] = {};

    for (int k0 = 0; k0 < K; k0 += GEMM_BK) {
        #pragma unroll
        for (int i = 0; i < 4; ++i) {
            int idx = tid + i * 256;
            int m = idx >> 4, kk = idx & 15;
            As[kk][m] = b2f(A[(size_t)(m0 + m) * K + (k0 + kk)]);
        }
        #pragma unroll
        for (int i = 0; i < 4; ++i) {
            int idx = tid + i * 256;
            int kk = idx >> 6, n = idx & 63;
            int kr = k0 + kk;
            int h = kr >> 3, d = kr & 7;   // attn row kr -> head h, dim d
            const bf16* src = (h < 64 ? qkv : agg) +
                ((size_t)b * 1536 + (size_t)(h & 63) * 24 + 16 + d) * 4096;
            Bs[kk][n] = b2f(src[n0 + n]);
        }
        __syncthreads();
        #pragma unroll
        for (int kk = 0; kk < GEMM_BK; ++kk) {
            float a[GEMM_TM], bb[GEMM_TN];
            #pragma unroll
            for (int i = 0; i < GEMM_TM; ++i) a[i] = As[kk][tm + i];
            #pragma unroll
            for (int j = 0; j < GEMM_TN; ++j) bb[j] = Bs[kk][tn + j];
            #pragma unroll
            for (int i = 0; i < GEMM_TM; ++i)
                #pragma unroll
                for (int j = 0; j < GEMM_TN; ++j)
                    acc[i][j] += a[i] * bb[j];
        }
        __syncthreads();
    }

    #pragma unroll
    for (int i = 0; i < GEMM_TM; ++i) {
        int m = m0 + tm + i;
        #pragma unroll
        for (int j = 0; j < GEMM_TN; ++j) {
            int n = n0 + tn + j;
            size_t off = (size_t)m * N + n;
            if (f32io) Of[off] = acc[i][j] + Xf[off];
            else       Ob[off] = f2b(acc[i][j] + b2f(Xb[off]));
        }
    }
}

// Fused depthwise 5x5 (pad 2) + grouped pointwise (8->8 per group).
__global__ __launch_bounds__(256) void dwpw_kernel(
    const bf16* __restrict__ qkv, const bf16* __restrict__ w_dw,
    const bf16* __restrict__ w_pw, bf16* __restrict__ agg)
{
    const int bg = blockIdx.z;
    const int b = bg / 192;
    const int g = bg % 192;
    const int ty0 = blockIdx.y * 16;
    const int tx0 = blockIdx.x * 16;

    __shared__ float s_in[8][20][20];
    __shared__ float s_wdw[8][25];
    __shared__ float s_wpw[8][8];

    const int tid = threadIdx.x;
    if (tid < 200) {
        int c = tid / 25, k = tid % 25;
        s_wdw[c][k] = b2f(w_dw[(size_t)(g * 8 + c) * 25 + k]);
    }
    if (tid < 64) {
        int o = tid >> 3, i = tid & 7;
        s_wpw[o][i] = b2f(w_pw[(size_t)(g * 8 + o) * 8 + i]);
    }

    const size_t chan_base = ((size_t)b * 1536 + g * 8) * 4096;
    for (int idx = tid; idx < 8 * 400; idx += 256) {
        int c = idx / 400;
        int rem = idx - c * 400;
        int yy = rem / 20;
        int xx = rem - yy * 20;
        int y = ty0 + yy - 2;
        int x = tx0 + xx - 2;
        float v = 0.f;
        if (y >= 0 && y < 64 && x >= 0 && x < 64)
            v = b2f(qkv[chan_base + (size_t)c * 4096 + y * 64 + x]);
        s_in[c][yy][xx] = v;
    }
    __syncthreads();

    const int py = tid >> 4;
    const int px = tid & 15;

    float dwv[8];
    #pragma unroll
    for (int c = 0; c < 8; ++c) {
        float s = 0.f;
        #pragma unroll
        for (int i = 0; i < 5; ++i)
            #pragma unroll
            for (int j = 0; j < 5; ++j)
                s += s_in[c][py + i][px + j] * s_wdw[c][i * 5 + j];
        dwv[c] = s;
    }
    const size_t out_pix = (size_t)(ty0 + py) * 64 + (tx0 + px);
    #pragma unroll
    for (int o = 0; o < 8; ++o) {
        float s = 0.f;
        #pragma unroll
        for (int i = 0; i < 8; ++i) s += dwv[i] * s_wpw[o][i];
        agg[chan_base + (size_t)o * 4096 + out_pix] = f2b(s);
    }
}

// vk[bh, d, e] = sum_n v[d,n]*relu(k[e,n]); row d=8 = sum_n relu(k[e,n])
__global__ __launch_bounds__(256) void vk_kernel(
    const bf16* __restrict__ qkv, const bf16* __restrict__ agg,
    float* __restrict__ vk)
{
    const int bh = blockIdx.x;   // 0..511
    const int b = bh >> 7;
    const int h = bh & 127;
    const bf16* base = (h < 64)
        ? (qkv + ((size_t)b * 1536 + h * 24) * 4096)
        : (agg + ((size_t)b * 1536 + (h - 64) * 24) * 4096);

    const int tid = threadIdx.x;
    float acc[9][8] = {};

    for (int n = tid; n < 4096; n += 256) {
        float kv[8], vv[8];
        #pragma unroll
        for (int e = 0; e < 8; ++e) kv[e] = fmaxf(b2f(base[(size_t)(8 + e) * 4096 + n]), 0.f);
        #pragma unroll
        for (int d = 0; d < 8; ++d) vv[d] = b2f(base[(size_t)(16 + d) * 4096 + n]);
        #pragma unroll
        for (int d = 0; d < 8; ++d)
            #pragma unroll
            for (int e = 0; e < 8; ++e)
                acc[d][e] += vv[d] * kv[e];
        #pragma unroll
        for (int e = 0; e < 8; ++e) acc[8][e] += kv[e];
    }

    __shared__ float red[4][72];
    const int lane = tid & 63, wave = tid >> 6;
    #pragma unroll
    for (int d = 0; d < 9; ++d) {
        #pragma unroll
        for (int e = 0; e < 8; ++e) {
            float v = acc[d][e];
            #pragma unroll
            for (int off = 32; off > 0; off >>= 1) v += __shfl_down(v, off, 64);
            if (lane == 0) red[wave][d * 8 + e] = v;
        }
    }
    __syncthreads();
    if (tid < 72) {
        float v = red[0][tid] + red[1][tid] + red[2][tid] + red[3][tid];
        vk[(size_t)bh * 72 + tid] = v;
    }
}

// attn written in place over v-rows (16..23) of each head.
__global__ __launch_bounds__(256) void attn_out_kernel(
    bf16* __restrict__ qkv, bf16* __restrict__ agg,
    const float* __restrict__ vk)
{
    const int b = blockIdx.z;
    const int h = blockIdx.y;
    const int n = blockIdx.x * 256 + threadIdx.x;
    bf16* base = (h < 64)
        ? (qkv + ((size_t)b * 1536 + h * 24) * 4096)
        : (agg + ((size_t)b * 1536 + (h - 64) * 24) * 4096);

    __shared__ float s_vk[72];
    if (threadIdx.x < 72)
        s_vk[threadIdx.x] = vk[((size_t)b * 128 + h) * 72 + threadIdx.x];
    __syncthreads();

    float q[8];
    #pragma unroll
    for (int e = 0; e < 8; ++e) q[e] = fmaxf(b2f(base[(size_t)e * 4096 + n]), 0.f);

    float o[9];
    #pragma unroll
    for (int d = 0; d < 9; ++d) {
        float s = 0.f;
        #pragma unroll
        for (int e = 0; e < 8; ++e) s += s_vk[d * 8 + e] * q[e];
        o[d] = s;
    }
    const float denom = o[8] + 1e-15f;
    #pragma unroll
    for (int d = 0; d < 8; ++d)
        base[(size_t)(16 + d) * 4096 + n] = f2b(o[d] / denom);
}

extern "C" void kernel_launch(void* const* d_in, const int* in_sizes, int n_in,
                              void* d_out, int out_size, void* d_ws, size_t ws_size,
                              hipStream_t stream) {
    const void* x      = d_in[0];
    const void* w_qkv  = d_in[1];
    const void* w_dw   = d_in[2];
    const void* w_pw   = d_in[3];
    const void* w_proj = d_in[4];

    // ws layout (bytes)
    char* ws = (char*)d_ws;
    int*  flag      = (int*)ws;                          // 4 B
    bf16* w_qkv_bf  = (bf16*)(ws + 256);                 // 1,572,864 B
    bf16* w_dw_bf   = (bf16*)(ws + 256 + 1572864);       //    76,800 B
    bf16* w_pw_bf   = (bf16*)(ws + 256 + 1572864 + 76800);           // 24,576 B
    bf16* w_proj_bf = (bf16*)(ws + 256 + 1572864 + 76800 + 24576);   // 1,048,576 B
    float* vkbf     = (float*)(ws + 256 + 1572864 + 76800 + 24576 + 1048576); // 147,456 B
    bf16* qkv       = (bf16*)(ws + 256 + 1572864 + 76800 + 24576 + 1048576 + 147456);
    bf16* agg       = qkv + (size_t)4 * 1536 * 4096;     // + 48 MiB each

    // 0. detect input dtype (writes flag; same work every call)
    detect_kernel<<<1, 256, 0, stream>>>((const unsigned short*)x, flag);

    // 0b. canonicalize weights to bf16
    convert_kernel<<<(786432 + 255) / 256, 256, 0, stream>>>(w_qkv, w_qkv_bf, 786432, flag);
    convert_kernel<<<(38400 + 255) / 256, 256, 0, stream>>>(w_dw, w_dw_bf, 38400, flag);
    convert_kernel<<<(12288 + 255) / 256, 256, 0, stream>>>(w_pw, w_pw_bf, 12288, flag);
    convert_kernel<<<(524288 + 255) / 256, 256, 0, stream>>>(w_proj, w_proj_bf, 524288, flag);

    // 1. qkv = w_qkv (1536x512) @ x[b] (512x4096)
    qkv_gemm_kernel<<<dim3(64, 24, 4), 256, 0, stream>>>(w_qkv_bf, x, qkv, flag);

    // 2. agg = grouped-PW(DW5x5(qkv))
    dwpw_kernel<<<dim3(4, 4, 4 * 192), 256, 0, stream>>>(qkv, w_dw_bf, w_pw_bf, agg);

    // 3. vk per (b, head)
    vk_kernel<<<dim3(512), 256, 0, stream>>>(qkv, agg, vkbf);

    // 4. attn (normalized) written over dead v-rows of qkv/agg
    attn_out_kernel<<<dim3(16, 128, 4), 256, 0, stream>>>(qkv, agg, vkbf);

    // 5. out = x + w_proj (512x1024) @ attn[b]
    proj_gemm_kernel<<<dim3(64, 8, 4), 256, 0, stream>>>(
        w_proj_bf, qkv, agg, x, d_out, flag);
}

// Round 5
// 319.999 us; speedup vs baseline: 2.9254x; 2.9254x over previous
//
#include <hip/hip_runtime.h>
#include <hip/hip_bf16.h>
#include <cstdint>
#include <cstddef>

// Shapes (fixed): B=4, C=512, H=W=64, N=4096, td=512. Inputs/outputs fp32
// (proven in R4). Compute in bf16 MFMA with fp32 accumulation.
//   x (4,512,4096) | w_qkv (1536,512) | w_dw (1536,25) | w_pw (1536,8) |
//   w_proj (512,1024) | out (4,512,4096) fp32
//
// ws layout (bytes; total ~114.6 MiB):
//   w_qkv_bf  1,572,864 | w_proj_bf 1,048,576 | vk 147,456 |
//   x_t (4,4096,512) bf16 16,777,216 | qkv 50,331,648 | agg 50,331,648
//
// attn is stored head-chunk-transposed over the dead v-rows of qkv/agg:
// chunk(b,h) = 4096 n x 8 d, d contiguous -> proj GEMM B^T staging is
// lane-contiguous for global_load_lds.

typedef __hip_bfloat16 bf16;
typedef __attribute__((ext_vector_type(8))) short short8;
typedef __attribute__((ext_vector_type(4))) float f32x4;

__device__ __forceinline__ float b2f(bf16 v) { return __bfloat162float(v); }
__device__ __forceinline__ bf16 f2b(float v) { return __float2bfloat16(v); }

__device__ __forceinline__ void async16(void* lds_base, const void* gaddr) {
    // dest = lds_base (wave-uniform) + lane*16; per-lane global address.
    __builtin_amdgcn_global_load_lds(
        (const __attribute__((address_space(1))) unsigned int*)gaddr,
        (__attribute__((address_space(3))) unsigned int*)lds_base,
        16, 0, 0);
}

// ---- weight fp32 -> bf16 ----
__global__ __launch_bounds__(256) void convert_kernel(
    const float* __restrict__ src, bf16* __restrict__ dst, int n)
{
    int i = blockIdx.x * 256 + threadIdx.x;
    if (i < n) dst[i] = f2b(src[i]);
}

// ---- x (4,512,4096) fp32 -> x_t (4,4096,512) bf16 ----
__global__ __launch_bounds__(256) void transpose_x_kernel(
    const float* __restrict__ x, bf16* __restrict__ x_t)
{
    __shared__ bf16 tile[32][33];
    const int b = blockIdx.z;
    const int c0 = blockIdx.y * 32;
    const int n0 = blockIdx.x * 32;
    const int tx = threadIdx.x & 31, ty = threadIdx.x >> 5;  // 32x8
    #pragma unroll
    for (int i = 0; i < 32; i += 8)
        tile[ty + i][tx] = f2b(x[((size_t)b * 512 + c0 + ty + i) * 4096 + n0 + tx]);
    __syncthreads();
    #pragma unroll
    for (int i = 0; i < 32; i += 8)
        x_t[((size_t)b * 4096 + n0 + ty + i) * 512 + c0 + tx] = tile[tx][ty + i];
}

// ---- MFMA GEMM, m97 structure: 128x128 tile, BK=32, 4 waves, 64x64/wave ----
// PROJ=false: C[b](1536x4096) bf16 = A(1536x512) * x_t[b]^T ; K=512
// PROJ=true:  out[b](512x4096) f32 = A(512x1024) * attn[b] + x[b] ; K=1024,
//             B^T gathered from head-chunked attn in qkv/agg v-rows.
template <bool PROJ>
__global__ __launch_bounds__(256) void mfma_gemm_kernel(
    const bf16* __restrict__ A, const bf16* __restrict__ xt_or_qkv,
    const bf16* __restrict__ agg, const float* __restrict__ X,
    void* __restrict__ Cout, int M, int K)
{
    constexpr int N = 4096;
    const int b = blockIdx.z;
    const int m_blk = blockIdx.y * 128;
    const int n_blk = blockIdx.x * 128;

    __shared__ short As[128 * 32];   // [row][32k], 64 B rows
    __shared__ short Bs[128 * 32];   // [n][32k] (B^T)

    const int tid = threadIdx.x;
    const int lane = tid & 63, wave = tid >> 6;
    const int wm = (wave >> 1) * 64, wn = (wave & 1) * 64;
    const int fm = lane & 15, fq = lane >> 4;

    f32x4 acc[4][4] = {};

    const short* Ag = (const short*)A;
    const short* Btg = PROJ ? nullptr
        : (const short*)(xt_or_qkv + (size_t)b * N * 512);  // x_t[b], K=512

    for (int k0 = 0; k0 < K; k0 += 32) {
        // stage A: 8 chunks of 16 rows; wave handles chunks {wave, wave+4}
        #pragma unroll
        for (int t0 = 0; t0 < 2; ++t0) {
            int t = wave + t0 * 4;
            int row = m_blk + t * 16 + (lane >> 2);
            int col = k0 + (lane & 3) * 8;
            async16(&As[t * 512], Ag + (size_t)row * K + col);
        }
        // stage B^T
        #pragma unroll
        for (int t0 = 0; t0 < 2; ++t0) {
            int t = wave + t0 * 4;
            int n = n_blk + t * 16 + (lane >> 2);
            if (!PROJ) {
                int col = k0 + (lane & 3) * 8;
                async16(&Bs[t * 512], Btg + (size_t)n * 512 + col);
            } else {
                int h = (k0 >> 3) + (lane & 3);      // 4 heads per k-tile
                const bf16* chunk = (h < 64 ? xt_or_qkv : agg) +
                    ((size_t)b * 1536 + (size_t)(h & 63) * 24 + 16) * 4096;
                async16(&Bs[t * 512], chunk + (size_t)n * 8);
            }
        }
        __syncthreads();   // drains vmcnt before ds_read

        short8 af[4], bfv[4];
        #pragma unroll
        for (int i = 0; i < 4; ++i)
            af[i] = *(const short8*)&As[(wm + i * 16 + fm) * 32 + fq * 8];
        #pragma unroll
        for (int j = 0; j < 4; ++j)
            bfv[j] = *(const short8*)&Bs[(wn + j * 16 + fm) * 32 + fq * 8];
        #pragma unroll
        for (int i = 0; i < 4; ++i)
            #pragma unroll
            for (int j = 0; j < 4; ++j)
                acc[i][j] = __builtin_amdgcn_mfma_f32_16x16x32_bf16(
                    af[i], bfv[j], acc[i][j], 0, 0, 0);
        __syncthreads();
    }

    // epilogue: C/D layout col=lane&15, row=(lane>>4)*4+reg
    if (!PROJ) {
        bf16* Cb = (bf16*)Cout + (size_t)b * M * N;
        #pragma unroll
        for (int i = 0; i < 4; ++i)
            #pragma unroll
            for (int j = 0; j < 4; ++j) {
                int n = n_blk + wn + j * 16 + fm;
                #pragma unroll
                for (int r = 0; r < 4; ++r) {
                    int m = m_blk + wm + i * 16 + fq * 4 + r;
                    Cb[(size_t)m * N + n] = f2b(acc[i][j][r]);
                }
            }
    } else {
        float* Ob = (float*)Cout + (size_t)b * M * N;
        const float* Xb = X + (size_t)b * M * N;
        #pragma unroll
        for (int i = 0; i < 4; ++i)
            #pragma unroll
            for (int j = 0; j < 4; ++j) {
                int n = n_blk + wn + j * 16 + fm;
                #pragma unroll
                for (int r = 0; r < 4; ++r) {
                    int m = m_blk + wm + i * 16 + fq * 4 + r;
                    size_t off = (size_t)m * N + n;
                    Ob[off] = acc[i][j][r] + Xb[off];
                }
            }
    }
}

// ---- fused depthwise 5x5 (pad 2) + grouped pointwise (8->8) ----
__global__ __launch_bounds__(256) void dwpw_kernel(
    const bf16* __restrict__ qkv, const float* __restrict__ w_dw,
    const float* __restrict__ w_pw, bf16* __restrict__ agg)
{
    const int bg = blockIdx.z;
    const int b = bg / 192;
    const int g = bg % 192;
    const int ty0 = blockIdx.y * 16;
    const int tx0 = blockIdx.x * 16;

    __shared__ float s_in[8][20][20];
    __shared__ float s_wdw[8][25];
    __shared__ float s_wpw[8][8];

    const int tid = threadIdx.x;
    if (tid < 200) {
        int c = tid / 25, k = tid % 25;
        s_wdw[c][k] = w_dw[(size_t)(g * 8 + c) * 25 + k];
    }
    if (tid < 64) {
        int o = tid >> 3, i = tid & 7;
        s_wpw[o][i] = w_pw[(size_t)(g * 8 + o) * 8 + i];
    }

    const size_t chan_base = ((size_t)b * 1536 + g * 8) * 4096;
    for (int idx = tid; idx < 8 * 400; idx += 256) {
        int c = idx / 400;
        int rem = idx - c * 400;
        int yy = rem / 20;
        int xx = rem - yy * 20;
        int y = ty0 + yy - 2;
        int x = tx0 + xx - 2;
        float v = 0.f;
        if (y >= 0 && y < 64 && x >= 0 && x < 64)
            v = b2f(qkv[chan_base + (size_t)c * 4096 + y * 64 + x]);
        s_in[c][yy][xx] = v;
    }
    __syncthreads();

    const int py = tid >> 4;
    const int px = tid & 15;

    float dwv[8];
    #pragma unroll
    for (int c = 0; c < 8; ++c) {
        float s = 0.f;
        #pragma unroll
        for (int i = 0; i < 5; ++i)
            #pragma unroll
            for (int j = 0; j < 5; ++j)
                s += s_in[c][py + i][px + j] * s_wdw[c][i * 5 + j];
        dwv[c] = s;
    }
    const size_t out_pix = (size_t)(ty0 + py) * 64 + (tx0 + px);
    #pragma unroll
    for (int o = 0; o < 8; ++o) {
        float s = 0.f;
        #pragma unroll
        for (int i = 0; i < 8; ++i) s += dwv[i] * s_wpw[o][i];
        agg[chan_base + (size_t)o * 4096 + out_pix] = f2b(s);
    }
}

// ---- vk[bh,d,e] = sum_n v[d,n]*relu(k[e,n]); row d=8 = sum relu(k) ----
__global__ __launch_bounds__(256) void vk_kernel(
    const bf16* __restrict__ qkv, const bf16* __restrict__ agg,
    float* __restrict__ vk)
{
    const int bh = blockIdx.x;   // 0..511
    const int b = bh >> 7;
    const int h = bh & 127;
    const bf16* base = (h < 64)
        ? (qkv + ((size_t)b * 1536 + h * 24) * 4096)
        : (agg + ((size_t)b * 1536 + (h - 64) * 24) * 4096);

    const int tid = threadIdx.x;
    float acc[9][8] = {};

    for (int n = tid; n < 4096; n += 256) {
        float kv[8], vv[8];
        #pragma unroll
        for (int e = 0; e < 8; ++e) kv[e] = fmaxf(b2f(base[(size_t)(8 + e) * 4096 + n]), 0.f);
        #pragma unroll
        for (int d = 0; d < 8; ++d) vv[d] = b2f(base[(size_t)(16 + d) * 4096 + n]);
        #pragma unroll
        for (int d = 0; d < 8; ++d)
            #pragma unroll
            for (int e = 0; e < 8; ++e)
                acc[d][e] += vv[d] * kv[e];
        #pragma unroll
        for (int e = 0; e < 8; ++e) acc[8][e] += kv[e];
    }

    __shared__ float red[4][72];
    const int lane = tid & 63, wave = tid >> 6;
    #pragma unroll
    for (int d = 0; d < 9; ++d) {
        #pragma unroll
        for (int e = 0; e < 8; ++e) {
            float v = acc[d][e];
            #pragma unroll
            for (int off = 32; off > 0; off >>= 1) v += __shfl_down(v, off, 64);
            if (lane == 0) red[wave][d * 8 + e] = v;
        }
    }
    __syncthreads();
    if (tid < 72) {
        float v = red[0][tid] + red[1][tid] + red[2][tid] + red[3][tid];
        vk[(size_t)bh * 72 + tid] = v;
    }
}

// ---- attn: head-chunk-transposed write over dead v-rows ----
// chunk(b,h)[n][d] at (base + 16*4096) + n*8 + d  (one 16-B store/thread)
__global__ __launch_bounds__(256) void attn_out_kernel(
    bf16* __restrict__ qkv, bf16* __restrict__ agg,
    const float* __restrict__ vk)
{
    const int b = blockIdx.z;
    const int h = blockIdx.y;
    const int n = blockIdx.x * 256 + threadIdx.x;
    bf16* base = (h < 64)
        ? (qkv + ((size_t)b * 1536 + h * 24) * 4096)
        : (agg + ((size_t)b * 1536 + (h - 64) * 24) * 4096);

    __shared__ float s_vk[72];
    if (threadIdx.x < 72)
        s_vk[threadIdx.x] = vk[((size_t)b * 128 + h) * 72 + threadIdx.x];
    __syncthreads();

    float q[8];
    #pragma unroll
    for (int e = 0; e < 8; ++e) q[e] = fmaxf(b2f(base[(size_t)e * 4096 + n]), 0.f);

    float o[9];
    #pragma unroll
    for (int d = 0; d < 9; ++d) {
        float s = 0.f;
        #pragma unroll
        for (int e = 0; e < 8; ++e) s += s_vk[d * 8 + e] * q[e];
        o[d] = s;
    }
    const float denom = o[8] + 1e-15f;

    union { bf16 hv[8]; uint4 u; } pk;
    #pragma unroll
    for (int d = 0; d < 8; ++d) pk.hv[d] = f2b(o[d] / denom);
    *(uint4*)((char*)(base + (size_t)16 * 4096) + (size_t)n * 16) = pk.u;
}

extern "C" void kernel_launch(void* const* d_in, const int* in_sizes, int n_in,
                              void* d_out, int out_size, void* d_ws, size_t ws_size,
                              hipStream_t stream) {
    const float* x      = (const float*)d_in[0];
    const float* w_qkv  = (const float*)d_in[1];
    const float* w_dw   = (const float*)d_in[2];
    const float* w_pw   = (const float*)d_in[3];
    const float* w_proj = (const float*)d_in[4];

    char* ws = (char*)d_ws;
    bf16* w_qkv_bf  = (bf16*)ws;                               // 1,572,864 B
    bf16* w_proj_bf = (bf16*)(ws + 1572864);                   // 1,048,576 B
    float* vkbf     = (float*)(ws + 1572864 + 1048576);        //   147,456 B
    bf16* x_t       = (bf16*)(ws + 1572864 + 1048576 + 147456);          // 16 MiB
    bf16* qkv       = x_t + (size_t)4 * 4096 * 512;            // 48 MiB
    bf16* agg       = qkv + (size_t)4 * 1536 * 4096;           // 48 MiB

    // 0. weight conversion + x transpose
    convert_kernel<<<3072, 256, 0, stream>>>(w_qkv, w_qkv_bf, 786432);
    convert_kernel<<<2048, 256, 0, stream>>>(w_proj, w_proj_bf, 524288);
    transpose_x_kernel<<<dim3(128, 16, 4), 256, 0, stream>>>(x, x_t);

    // 1. qkv = w_qkv (1536x512) @ x[b]  (MFMA, B^T from x_t)
    mfma_gemm_kernel<false><<<dim3(32, 12, 4), 256, 0, stream>>>(
        w_qkv_bf, x_t, nullptr, nullptr, qkv, 1536, 512);

    // 2. agg = grouped-PW(DW5x5(qkv))
    dwpw_kernel<<<dim3(4, 4, 4 * 192), 256, 0, stream>>>(qkv, w_dw, w_pw, agg);

    // 3. vk per (b, head)
    vk_kernel<<<dim3(512), 256, 0, stream>>>(qkv, agg, vkbf);

    // 4. attn (normalized), head-chunk-transposed over dead v-rows
    attn_out_kernel<<<dim3(16, 128, 4), 256, 0, stream>>>(qkv, agg, vkbf);

    // 5. out = x + w_proj (512x1024) @ attn[b]  (MFMA, B^T from chunks)
    mfma_gemm_kernel<true><<<dim3(32, 4, 4), 256, 0, stream>>>(
        w_proj_bf, qkv, agg, x, d_out, 512, 1024);
}